// Round 1
// baseline (69.165 us; speedup 1.0000x reference)
//
#include <hip/hip_runtime.h>

// QuantumCircuit 16q/4layers/batch512 via EXACT MPS (bond dim 16),
// MEET-IN-THE-MIDDLE transfer sweep.
//
// Math identical to the previous (verified) kernel, restructured:
//  - Left env:  Lam^(s)_j[b][bp] = sum_{c,a,ap} conj(r3_s[a][j^c][b]) Lam^(s-1)_c[a][ap] r3_s[ap][j^c][bp]
//  - Right env: R^(s)_c[a][ap]   = sum_{j,b,bp} conj(r3_s[a][j^c][b]) R^(s+1)_j[b][bp]   r3_s[ap][j^c][bp]
//    which is the SAME contraction with r3's 1st/3rd indices swapped.
//  - Base: R^(15)[a][ap] = sum_k conj(r15[a][k]) r15[ap][k]  (both blocks)
//  - Merge: M = sum_c sum_{a,ap} Lam^(7)_c[a][ap] * R^(8)_c[a][ap]  (real part)
// Left sweep sites 1..7, right sweep sites 14..8, both advanced per loop
// iteration -> serial depth 7 steps x 2 phases (was 14 x 3).
//
// All site tensors r3 are Lam-independent -> precomputed once into LDS in
// transposed layout wT[m][beta][alpha] (= r3[alpha][m][beta]; right sites
// stored index-swapped), so BOTH phases read rows contiguously (b128-able).
// Pads: w/Lam rows 10 float2 (80B, 16B-aligned), Tt rows 18 float2 (144B):
// bank strides 20/36 dwords -> <=2-way (free).

#define NQ 16

__device__ __forceinline__ float2 cmul(float2 a, float2 b){
    return make_float2(a.x*b.x - a.y*b.y, a.x*b.y + a.y*b.x);
}
__device__ __forceinline__ float2 cmulc(float2 a, float2 b){   // conj(a)*b
    return make_float2(a.x*b.x + a.y*b.y, a.x*b.y - a.y*b.x);
}
__device__ __forceinline__ void cfma(float2& acc, float2 a, float2 b){      // acc += a*b
    acc.x = fmaf(a.x, b.x, fmaf(-a.y, b.y, acc.x));
    acc.y = fmaf(a.x, b.y, fmaf( a.y, b.x, acc.y));
}
__device__ __forceinline__ void cfmac(float2& acc, float2 a, float2 b){     // acc += conj(a)*b
    acc.x = fmaf(a.x, b.x, fmaf( a.y, b.y, acc.x));
    acc.y = fmaf(a.x, b.y, fmaf(-a.y, b.x, acc.y));
}

// Rot(phi,theta,omega) = RZ(omega) RY(theta) RZ(phi)
__device__ __forceinline__ void make_rot(const float* __restrict__ params, int L, int q, float u[8]){
    const float* pp = params + (L*NQ + q)*3;
    float phi = pp[0], th = pp[1], om = pp[2];
    float s, c;     sincosf(0.5f*th, &s, &c);
    float sap, cap; sincosf(0.5f*(phi+om), &sap, &cap);
    float sam, cam; sincosf(0.5f*(phi-om), &sam, &cam);
    u[0] =  c*cap; u[1] = -c*sap;
    u[2] = -s*cam; u[3] = -s*sam;
    u[4] =  s*cam; u[5] = -s*sam;
    u[6] =  c*cap; u[7] =  c*sap;
}
__device__ __forceinline__ void fuse_ry(float a, float u[8]){
    float sa, ca; sincosf(0.5f*a, &sa, &ca);
    float f0r =  u[0]*ca + u[2]*sa, f0i =  u[1]*ca + u[3]*sa;
    float f1r = -u[0]*sa + u[2]*ca, f1i = -u[1]*sa + u[3]*ca;
    float g0r =  u[4]*ca + u[6]*sa, g0i =  u[5]*ca + u[7]*sa;
    float g1r = -u[4]*sa + u[6]*ca, g1i = -u[5]*sa + u[7]*ca;
    u[0]=f0r; u[1]=f0i; u[2]=f1r; u[3]=f1i; u[4]=g0r; u[5]=g0i; u[6]=g1r; u[7]=g1i;
}

__launch_bounds__(64)
__global__ void qmps_kernel(const float* __restrict__ inputs,
                            const float* __restrict__ params,
                            float* __restrict__ out)
{
    __shared__ __align__(16) float2 U[3][NQ][2][2];       // U[l][q] = Rot(params[l+1,q])
    __shared__ __align__(16) float2 v[NQ][2];             // Rot(params[0,q])*RY(x_q)|0>
    __shared__ __align__(16) float2 w[14][2][8][10];      // wT[site-1][m][beta][alpha]; right sites swapped
    __shared__ __align__(16) float2 Lam[2][2][2][8][10];  // [env L/R][buf][blk][row][col(pad)]
    __shared__ __align__(16) float2 Tt[2][2][8][18];      // [env][j][col_b][r=c*8+a (pad)]
    __shared__ __align__(16) float2 B0[2][8];
    __shared__ __align__(16) float2 r15s[8][2];

    const int t = threadIdx.x;            // one wave
    const int b = blockIdx.x;             // batch element

    // ---- phase 0: gate matrices + init vectors ----
    if (t < 48) {
        int l = t >> 4, q = t & 15;
        float u[8]; make_rot(params, l+1, q, u);
        U[l][q][0][0] = make_float2(u[0],u[1]); U[l][q][0][1] = make_float2(u[2],u[3]);
        U[l][q][1][0] = make_float2(u[4],u[5]); U[l][q][1][1] = make_float2(u[6],u[7]);
    } else {
        int q = t - 48;
        float u[8]; make_rot(params, 0, q, u);
        fuse_ry(inputs[b*NQ + q], u);
        v[q][0] = make_float2(u[0],u[1]);
        v[q][1] = make_float2(u[4],u[5]);
    }
    __syncthreads();

    // ---- phase 1: ALL site tensors (hoisted out of the sweep) + edges ----
    // 14 sites x 128 entries = 1792 = 28/lane. site uniform per kk (e>>7).
    #pragma unroll 4
    for (int kk = 0; kk < 28; ++kk) {
        int e     = t + (kk << 6);
        int ws    = e >> 7;               // 0..13
        int idx   = e & 127;
        int alpha = idx & 7, beta = (idx >> 3) & 7, m = (idx >> 6) & 1;
        int site  = ws + 1;               // 1..14
        // left sites store r3[alpha][m][beta]; right sites store r3[beta][m][alpha]
        int uu = (site <= 7) ? alpha : beta;    // aL bits (c1..c3)
        int dd = (site <= 7) ? beta  : alpha;   // aR bits (d1..d3)
        int c1 = uu & 1, c2 = (uu >> 1) & 1, c3 = (uu >> 2) & 1;
        int d1 = dd & 1, d2 = (dd >> 1) & 1, d3 = (dd >> 2) & 1;
        float2 val = cmul(U[2][site][m][d3],
                     cmul(U[1][site][d3^c3][d2],
                     cmul(U[0][site][d2^c2][d1], v[site][d1^c1])));
        w[ws][m][beta][alpha] = val;
    }
    if (t < 16) {
        // site 0: B0[j][ap] = U3[j,d3] U2[d3,d2] U1[d2,d1] v[d1]
        int j = t >> 3, ap = t & 7;
        int d1 = ap & 1, d2 = (ap>>1)&1, d3 = (ap>>2)&1;
        B0[j][ap] = cmul(U[2][0][j][d3],
                    cmul(U[1][0][d3][d2],
                    cmul(U[0][0][d2][d1], v[0][d1])));
    } else if (t < 32) {
        // site 15: r15[a][k] = sum_s U3[k,s3] U2[s3^c3,s2] U1[s2^c2,s1] v[s1^c1]
        int t2 = t - 16;
        int a = t2 >> 1, k = t2 & 1;
        int c1 = a & 1, c2 = (a>>1)&1, c3 = (a>>2)&1;
        float2 in1[2], in2[2];
        #pragma unroll
        for (int s2 = 0; s2 < 2; ++s2) {
            float2 acc = make_float2(0.f, 0.f);
            #pragma unroll
            for (int s1 = 0; s1 < 2; ++s1) cfma(acc, U[0][15][s2^c2][s1], v[15][s1^c1]);
            in1[s2] = acc;
        }
        #pragma unroll
        for (int s3 = 0; s3 < 2; ++s3) {
            float2 acc = make_float2(0.f, 0.f);
            #pragma unroll
            for (int s2 = 0; s2 < 2; ++s2) cfma(acc, U[1][15][s3^c3][s2], in1[s2]);
            in2[s3] = acc;
        }
        float2 acc = make_float2(0.f, 0.f);
        #pragma unroll
        for (int s3 = 0; s3 < 2; ++s3) cfma(acc, U[2][15][k][s3], in2[s3]);
        r15s[a][k] = acc;
    }
    __syncthreads();

    // ---- phase 2: env inits. L: z_c conj(B0[c,b])B0[c,b'].  R: sum_k conj(r15[a,k])r15[ap,k] (both blocks) ----
    #pragma unroll
    for (int h = 0; h < 2; ++h) {
        int e = t + (h << 6);
        int c = e >> 6, aa = (e >> 3) & 7, ap = e & 7;
        float2 valL = cmulc(B0[c][aa], B0[c][ap]);
        float  s    = c ? -1.f : 1.f;
        Lam[0][0][c][aa][ap] = make_float2(s*valL.x, s*valL.y);
        float2 valR = cmulc(r15s[aa][0], r15s[ap][0]);
        cfmac(valR, r15s[aa][1], r15s[ap][1]);
        Lam[1][0][c][aa][ap] = valR;      // c-independent base
    }
    __syncthreads();

    // ---- sweep: 7 steps, each advances BOTH envs (L at site 1+k, R at site 14-k) ----
    int cur = 0;
    #pragma unroll
    for (int k = 0; k < 7; ++k) {
        // phase A: T[j][c*8+a][bb] = sum_ap X_c[a][ap] * w_orig[ap][j^c][bb]
        {
            const int c = t >> 5, a = (t >> 2) & 7, bq = t & 3;
            const int r = c*8 + a;
            #pragma unroll
            for (int env = 0; env < 2; ++env) {
                const int slot = env ? (13 - k) : k;
                const float2* X = &Lam[env][cur][c][a][0];
                float2 xr[8];
                #pragma unroll
                for (int ap = 0; ap < 8; ++ap) xr[ap] = X[ap];   // contiguous -> b128
                #pragma unroll
                for (int j = 0; j < 2; ++j) {
                    const float2* w0 = &w[slot][j^c][bq  ][0];   // w_orig[.][j^c][bq]
                    const float2* w1 = &w[slot][j^c][bq+4][0];
                    float2 acc0 = make_float2(0.f,0.f), acc1 = make_float2(0.f,0.f);
                    #pragma unroll
                    for (int ap = 0; ap < 8; ++ap) {
                        cfma(acc0, xr[ap], w0[ap]);
                        cfma(acc1, xr[ap], w1[ap]);
                    }
                    Tt[env][j][bq  ][r] = acc0;
                    Tt[env][j][bq+4][r] = acc1;
                }
            }
        }
        __syncthreads();
        // phase B: Y_j[bb][bp] = sum_{c,a} conj(w_orig[a][j^c][bb]) * T[j][c*8+a][bp]
        {
            const int j = t >> 5, bb = (t >> 2) & 7, bq = t & 3;
            #pragma unroll
            for (int env = 0; env < 2; ++env) {
                const int slot = env ? (13 - k) : k;
                const float2* p0 = &w[slot][j  ][bb][0];   // c=0 row
                const float2* p1 = &w[slot][j^1][bb][0];   // c=1 row
                float2 wr0[8], wr1[8];
                #pragma unroll
                for (int a2 = 0; a2 < 8; ++a2) { wr0[a2] = p0[a2]; wr1[a2] = p1[a2]; }
                #pragma unroll
                for (int h = 0; h < 2; ++h) {
                    const int bp = bq + (h << 2);
                    const float2* trow = &Tt[env][j][bp][0];     // 16 contiguous
                    float2 acc = make_float2(0.f, 0.f);
                    #pragma unroll
                    for (int a2 = 0; a2 < 8; ++a2) cfmac(acc, wr0[a2], trow[a2]);
                    #pragma unroll
                    for (int a2 = 0; a2 < 8; ++a2) cfmac(acc, wr1[a2], trow[8 + a2]);
                    Lam[env][cur^1][j][bb][bp] = acc;
                }
            }
        }
        __syncthreads();
        cur ^= 1;
    }

    // ---- merge: M = Re( sum_c sum_{a,ap} LamL_c[a][ap] * LamR_c[a][ap] ) ----
    float m = 0.f;
    #pragma unroll
    for (int h = 0; h < 2; ++h) {
        int e = t + (h << 6);
        int c = e >> 6, aa = (e >> 3) & 7, ap = e & 7;
        float2 L = Lam[0][cur][c][aa][ap];
        float2 R = Lam[1][cur][c][aa][ap];
        m += L.x*R.x - L.y*R.y;
    }
    #pragma unroll
    for (int off = 32; off > 0; off >>= 1) m += __shfl_down(m, off, 64);
    if (t == 0) out[b] = m;
}

extern "C" void kernel_launch(void* const* d_in, const int* in_sizes, int n_in,
                              void* d_out, int out_size, void* d_ws, size_t ws_size,
                              hipStream_t stream) {
    (void)n_in; (void)out_size; (void)d_ws; (void)ws_size;
    const float* inputs = (const float*)d_in[0];   // (B,16) f32
    const float* params = (const float*)d_in[1];   // (4,16,3) f32
    float* out = (float*)d_out;                    // (B,) f32
    const int B = in_sizes[0] / NQ;
    qmps_kernel<<<B, 64, 0, stream>>>(inputs, params, out);
}